// Round 7
// baseline (1834.750 us; speedup 1.0000x reference)
//
#include <hip/hip_runtime.h>

// Residual VQ: B=8,T=4096,D=128 -> N=32768 rows; 8 codebooks x 1024 codes.
// Outputs concat in d_out (float): codes [N*8], quantized [N*128], loss [1].
//
// R7: lane=row decomposition (wave = 64 rows x 16 codes/pass). B is read
// with wave-uniform addresses DIRECTLY FROM cbw (input, never written by any
// kernel in the graph) -> scalar s_load path with no coherence hazard.
// A: one broadcast ds_read_b128 per wave per k4. c2 staged to LDS via
// vector loads. Loss: per-block slots summed in fixed order (no atomics).
// 512 blocks x 512 thr.

#define N_ROWS 32768
#define DIM    128
#define KCB    1024
#define NCB    8
#define LDA    132         // padded LDS row stride (floats)

#define MB     64          // rows per block (= lanes per wave)
#define CW     16          // codes per wave per pass
#define PCODES 128         // codes per pass (8 waves x 16)
#define NPASS  (KCB / PCODES)  // 8
#define NBLK   (N_ROWS / MB)   // 512

// c2[code] = numpy-pairwise sum over k of cb[code][k]^2 (n=128 pairwise, 8 accums)
__global__ __launch_bounds__(256) void c2_kernel(const float* __restrict__ cbw,
                                                 float* __restrict__ c2g) {
#pragma clang fp contract(off)
    int code = blockIdx.x * 256 + threadIdx.x;  // 0..8191
    const float* row = cbw + (size_t)code * DIM;
    float s[8];
    for (int j = 0; j < 8; ++j) { float x = row[j]; s[j] = x * x; }
    for (int m = 1; m < 16; ++m)
        for (int j = 0; j < 8; ++j) { float x = row[m * 8 + j]; float p = x * x; s[j] += p; }
    c2g[code] = ((s[0] + s[1]) + (s[2] + s[3])) + ((s[4] + s[5]) + (s[6] + s[7]));
}

__global__ __launch_bounds__(512) void rvq_kernel(
    const float* __restrict__ emb, const float* __restrict__ cbw,
    const float* __restrict__ c2g, float* __restrict__ out,
    double* __restrict__ slots)
{
    __shared__ float  a_lds[MB * LDA];     // residual [row][k], padded (33792 B)
    __shared__ float  c2_lds[KCB];         // current cb's c2 (4096 B)
    __shared__ float  r2_lds[MB];
    __shared__ float  scrP[8 * MB];        // pairwise r2 partials s_0..s_7
    __shared__ float  scrF[8 * MB];        // per-wave argmin values
    __shared__ int    scrI[8 * MB];        // per-wave argmin indices
    __shared__ double scrL[8];             // per-wave loss partials
    __shared__ int    codes_lds[NCB * MB];

    const int tid  = threadIdx.x;
    const int lane = tid & 63;                                  // = row
    const int wv   = __builtin_amdgcn_readfirstlane(tid >> 6);  // wave id 0..7
    const size_t base = (size_t)blockIdx.x * MB;

    // ---- stage embeddings -> a_lds (residual) ----
    for (int s = 0; s < 4; ++s) {
        int f4 = s * 512 + tid;          // 0..2047 float4s
        int r = f4 >> 5, k4 = f4 & 31;
        float4 v = *(const float4*)(emb + (base + r) * DIM + (size_t)k4 * 4);
        *(float4*)(a_lds + r * LDA + k4 * 4) = v;
    }
    __syncthreads();

    // ---- initial r2: numpy pairwise (8 accums s_q; thread q computes s_q) ----
    {
#pragma clang fp contract(off)
        int r = tid & 63, q = tid >> 6;   // q in 0..7
        float x = a_lds[r * LDA + q]; float sq = x * x;
        for (int m = 1; m < 16; ++m) {
            float y = a_lds[r * LDA + m * 8 + q]; float p = y * y; sq += p;
        }
        scrP[q * MB + r] = sq;
    }
    __syncthreads();
    if (tid < MB) {
#pragma clang fp contract(off)
        float s0 = scrP[tid],          s1 = scrP[MB + tid];
        float s2 = scrP[2 * MB + tid], s3 = scrP[3 * MB + tid];
        float s4 = scrP[4 * MB + tid], s5 = scrP[5 * MB + tid];
        float s6 = scrP[6 * MB + tid], s7 = scrP[7 * MB + tid];
        r2_lds[tid] = ((s0 + s1) + (s2 + s3)) + ((s4 + s5) + (s6 + s7));
    }
    // (per-cb top barrier below covers r2_lds visibility)

    const float* ar = a_lds + lane * LDA;   // this lane's row

    for (int cb = 0; cb < NCB; ++cb) {
        const float* cbbase = cbw + (size_t)cb * KCB * DIM;

        // stage this codebook's c2 into LDS (per-lane VECTOR loads; ws-coherent)
        if (tid < 256) {
            float4 cv = *(const float4*)(c2g + cb * KCB + tid * 4);
            *(float4*)(c2_lds + tid * 4) = cv;
        }
        __syncthreads();  // c2 + r2 + residual(a_lds) updates visible

        float minv = 3.4e38f; int mini = 0;
        const float r2v = r2_lds[lane];

        for (int pass = 0; pass < NPASS; ++pass) {
            // wave-uniform B slice: codes c0..c0+15 straight from cbw
            const int c0 = pass * PCODES + wv * CW;
            const float* __restrict__ bw = cbbase + (size_t)c0 * DIM;

            float acc[CW];
#pragma unroll
            for (int c = 0; c < CW; ++c) acc[c] = 0.f;

            // k ascending fp32 fma chain per (row,code). A: one broadcast
            // ds_read_b128 per wave per k4. B: wave-uniform s_load_dwordx4
            // from the immutable input codebook.
#pragma unroll 2
            for (int k4 = 0; k4 < 32; ++k4) {
                float4 av = *(const float4*)(ar + k4 * 4);
                const float* __restrict__ bk = bw + k4 * 4;
#pragma unroll
                for (int c = 0; c < CW; ++c) {
                    float b0 = bk[c * DIM + 0];
                    float b1 = bk[c * DIM + 1];
                    float b2 = bk[c * DIM + 2];
                    float b3 = bk[c * DIM + 3];
                    acc[c] = fmaf(av.x, b0, acc[c]);
                    acc[c] = fmaf(av.y, b1, acc[c]);
                    acc[c] = fmaf(av.z, b2, acc[c]);
                    acc[c] = fmaf(av.w, b3, acc[c]);
                }
            }
            // epilogue: d2 = fl(fl(r2 - 2*dot) + c2), running argmin (ascending idx)
            {
#pragma clang fp contract(off)
#pragma unroll
                for (int c = 0; c < CW; ++c) {
                    float t  = r2v - 2.0f * acc[c];
                    float d2 = t + c2_lds[c0 + c];
                    int   cg = c0 + c;
                    if (d2 < minv) { minv = d2; mini = cg; }
                }
            }
        }

        // cross-wave argmin combine (8 waves), ties -> lowest code index
        scrF[wv * MB + lane] = minv;
        scrI[wv * MB + lane] = mini;
        __syncthreads();
        if (tid < MB) {
            float v = scrF[tid]; int ix = scrI[tid];
            for (int w = 1; w < 8; ++w) {
                float v2 = scrF[w * MB + tid];
                int  ix2 = scrI[w * MB + tid];
                if (v2 < v || (v2 == v && ix2 < ix)) { v = v2; ix = ix2; }
            }
            codes_lds[cb * MB + tid] = ix;
        }
        __syncthreads();

        // residual update + loss + next-r2 pairwise partials (numpy order preserved)
        {
#pragma clang fp contract(off)
            int r = tid & 63, q = tid >> 6;   // q 0..7 -> accumulator s_q
            int widx = codes_lds[cb * MB + r];
            const float* ql = cbbase + (size_t)widx * DIM;
            float sq = 0.f;
            double lacc = 0.0;
            for (int m = 0; m < 16; ++m) {
                int k = m * 8 + q;
                float a = a_lds[r * LDA + k];
                float qv = ql[k];
                float n = a - qv;             // new residual (exact ref op)
                a_lds[r * LDA + k] = n;
                float p = n * n;              // loss element, fp32-rounded
                if (m == 0) sq = p; else sq += p;
                lacc += (double)p;
            }
            scrP[q * MB + r] = sq;
            for (int off = 32; off > 0; off >>= 1) lacc += __shfl_down(lacc, off, 64);
            if (lane == 0) scrL[wv] = lacc;
        }
        __syncthreads();
        if (tid == 0) {
            double s = 0.0;
            for (int w = 0; w < 8; ++w) s += scrL[w];   // fixed order
            slots[(size_t)blockIdx.x * NCB + cb] = s;
        }
        if (tid < MB) {
#pragma clang fp contract(off)
            float s0 = scrP[tid],          s1 = scrP[MB + tid];
            float s2 = scrP[2 * MB + tid], s3 = scrP[3 * MB + tid];
            float s4 = scrP[4 * MB + tid], s5 = scrP[5 * MB + tid];
            float s6 = scrP[6 * MB + tid], s7 = scrP[7 * MB + tid];
            r2_lds[tid] = ((s0 + s1) + (s2 + s3)) + ((s4 + s5) + (s6 + s7));
        }
    }
    __syncthreads();

    // ---- write codes (as float) ----
    if (tid < MB) {
        int r = tid;
        float4 u, v;
        u.x = (float)codes_lds[0 * MB + r]; u.y = (float)codes_lds[1 * MB + r];
        u.z = (float)codes_lds[2 * MB + r]; u.w = (float)codes_lds[3 * MB + r];
        v.x = (float)codes_lds[4 * MB + r]; v.y = (float)codes_lds[5 * MB + r];
        v.z = (float)codes_lds[6 * MB + r]; v.w = (float)codes_lds[7 * MB + r];
        *(float4*)(out + (base + r) * NCB)     = u;
        *(float4*)(out + (base + r) * NCB + 4) = v;
    }

    // ---- quantized = emb + (quant - emb), quant = sequential fp32 sum of codewords ----
    {
#pragma clang fp contract(off)
        int r = tid >> 3, q8 = tid & 7;    // 64 rows x 8 col-chunks of 16 floats
        size_t rg = base + r;
        int cds[NCB];
        for (int cb = 0; cb < NCB; ++cb) cds[cb] = codes_lds[cb * MB + r];
        float* qout = out + (size_t)N_ROWS * NCB;
        for (int ii = 0; ii < 4; ++ii) {
            int k = q8 * 16 + ii * 4;
            float4 qv = make_float4(0.f, 0.f, 0.f, 0.f);
            for (int cb = 0; cb < NCB; ++cb) {
                float4 cv = *(const float4*)(cbw + ((size_t)cb * KCB + cds[cb]) * DIM + k);
                qv.x += cv.x; qv.y += cv.y; qv.z += cv.z; qv.w += cv.w;
            }
            float4 ev = *(const float4*)(emb + rg * DIM + k);
            float4 ov;
            ov.x = ev.x + (qv.x - ev.x);
            ov.y = ev.y + (qv.y - ev.y);
            ov.z = ev.z + (qv.z - ev.z);
            ov.w = ev.w + (qv.w - ev.w);
            *(float4*)(qout + rg * DIM + k) = ov;
        }
    }
}

// Deterministic loss finish: fixed-order sum over blocks, numpy/ref op order.
__global__ __launch_bounds__(64) void finish_loss_kernel(const double* __restrict__ slots,
                                                         float* __restrict__ out_loss) {
    if (threadIdx.x == 0 && blockIdx.x == 0) {
        float l = 0.f;
        for (int cb = 0; cb < NCB; ++cb) {
            double s = 0.0;
            for (int b = 0; b < NBLK; ++b) s += slots[(size_t)b * NCB + cb];
            float m = (float)(s / 4194304.0);   // mean over N*D
            l = l + m;                          // fp32 sequential adds (ref order)
        }
        out_loss[0] = l / 8.0f;
    }
}

extern "C" void kernel_launch(void* const* d_in, const int* in_sizes, int n_in,
                              void* d_out, int out_size, void* d_ws, size_t ws_size,
                              hipStream_t stream) {
    const float* emb = (const float*)d_in[0];   // [32768,128] fp32
    const float* cbw = (const float*)d_in[1];   // [8,1024,128] fp32
    float* out = (float*)d_out;
    double* slots = (double*)d_ws;                        // 512*8 doubles (32 KB)
    float* c2g = (float*)((char*)d_ws + 32768);           // 8192 floats (32 KB)

    hipLaunchKernelGGL(c2_kernel, dim3(32), dim3(256), 0, stream, cbw, c2g);
    hipLaunchKernelGGL(rvq_kernel, dim3(NBLK), dim3(512), 0, stream,
                       emb, cbw, c2g, out, slots);
    hipLaunchKernelGGL(finish_loss_kernel, dim3(1), dim3(64), 0, stream, slots,
                       out + (size_t)N_ROWS * NCB + (size_t)N_ROWS * DIM);
}